// Round 6
// baseline (510.929 us; speedup 1.0000x reference)
//
#include <hip/hip_runtime.h>
#include <hip/hip_bf16.h>
#include <stdint.h>

typedef unsigned short u16;
typedef __attribute__((ext_vector_type(4))) unsigned int u32x4;
typedef __attribute__((ext_vector_type(8))) __bf16 bfx8;
typedef __attribute__((ext_vector_type(4))) float f32x4;

#define PI_F 3.14159265358979323846f

__device__ __forceinline__ float bf2f(u16 u) {
    unsigned v = ((unsigned)u) << 16; float f; __builtin_memcpy(&f, &v, 4); return f;
}
__device__ __forceinline__ u16 f2bf(float f) {
    unsigned u; __builtin_memcpy(&u, &f, 4);
    unsigned r = (u + 0x7fffu + ((u >> 16) & 1u)) >> 16; return (u16)r;
}

// global -> LDS direct DMA, 16B per lane. LDS dest must be lane-linear.
__device__ __forceinline__ void glds16(const u16* g, const u16* l) {
    __builtin_amdgcn_global_load_lds(
        (const __attribute__((address_space(1))) unsigned int*)(unsigned long long)g,
        (__attribute__((address_space(3))) unsigned int*)(unsigned int)(unsigned long long)l,
        16, 0, 0);
}

// ---------------------------------------------------------------------------
// Generic tiled transpose + f32->bf16 convert:  out[c][r] = in[r][c], batched.
// ---------------------------------------------------------------------------
__global__ __launch_bounds__(256)
void tconv_kernel(const float* __restrict__ in, u16* __restrict__ out,
                  int R, int C, long inBatch, long outBatch)
{
    __shared__ float tile[64][65];
    const int tx = threadIdx.x & 63;
    const int ty = threadIdx.x >> 6;
    const int bc = blockIdx.x * 64;
    const int br = blockIdx.y * 64;
    const float* ip = in + (long)blockIdx.z * inBatch;
    u16* op = out + (long)blockIdx.z * outBatch;

    #pragma unroll
    for (int rr = ty; rr < 64; rr += 4) {
        int r = br + rr, c = bc + tx;
        tile[rr][tx] = (r < R && c < C) ? ip[(long)r * C + c] : 0.f;
    }
    __syncthreads();
    #pragma unroll
    for (int rr = ty; rr < 64; rr += 4) {
        int oc = bc + rr;
        int orr = br + tx;
        if (oc < C && orr < R)
            op[(long)oc * R + orr] = f2bf(tile[tx][rr]);
    }
}

// ---------------------------------------------------------------------------
// LayerNorm (+ optional rank-1 q/k projections + tanh/cos/sin).
// ---------------------------------------------------------------------------
template<bool DO_QK>
__global__ __launch_bounds__(256)
void ln_kernel(const float* __restrict__ X, const float* __restrict__ w,
               const float* __restrict__ b, u16* __restrict__ Ybf,
               const float* __restrict__ WQ, const float* __restrict__ WK,
               float* __restrict__ cqA, float* __restrict__ sqA,
               float* __restrict__ ckA, float* __restrict__ skA)
{
    __shared__ float yrow[1024];
    __shared__ float wsum[4], wsq[4];
    const int row = blockIdx.x;
    const int tid = threadIdx.x;
    const int lane = tid & 63;
    const int wv = tid >> 6;

    const float4 xv = ((const float4*)(X + (long)row * 1024))[tid];
    float s  = xv.x + xv.y + xv.z + xv.w;
    float sq = xv.x*xv.x + xv.y*xv.y + xv.z*xv.z + xv.w*xv.w;
    #pragma unroll
    for (int off = 32; off; off >>= 1) {
        s  += __shfl_down(s, off);
        sq += __shfl_down(sq, off);
    }
    if (lane == 0) { wsum[wv] = s; wsq[wv] = sq; }
    __syncthreads();
    const float ts = wsum[0] + wsum[1] + wsum[2] + wsum[3];
    const float tq = wsq[0] + wsq[1] + wsq[2] + wsq[3];
    const float mean = ts * (1.f / 1024.f);
    const float var  = tq * (1.f / 1024.f) - mean * mean;
    const float rstd = rsqrtf(var + 1e-5f);

    const float4 wv4 = ((const float4*)w)[tid];
    const float4 bv4 = ((const float4*)b)[tid];
    const float y0 = (xv.x - mean) * rstd * wv4.x + bv4.x;
    const float y1 = (xv.y - mean) * rstd * wv4.y + bv4.y;
    const float y2 = (xv.z - mean) * rstd * wv4.z + bv4.z;
    const float y3 = (xv.w - mean) * rstd * wv4.w + bv4.w;

    uint2 p;
    p.x = (unsigned)f2bf(y0) | ((unsigned)f2bf(y1) << 16);
    p.y = (unsigned)f2bf(y2) | ((unsigned)f2bf(y3) << 16);
    ((uint2*)(Ybf + (long)row * 1024))[tid] = p;

    if (DO_QK) {
        yrow[tid*4+0] = y0; yrow[tid*4+1] = y1;
        yrow[tid*4+2] = y2; yrow[tid*4+3] = y3;
        __syncthreads();
        #pragma unroll
        for (int i = 0; i < 4; ++i) {
            const int h = wv * 4 + i;
            const float* wqp = WQ + (long)h * 1024;
            const float* wkp = WK + (long)h * 1024;
            float dq = 0.f, dk = 0.f;
            #pragma unroll
            for (int j = 0; j < 16; ++j) {
                const float yv = yrow[lane + 64*j];
                dq = fmaf(yv, wqp[lane + 64*j], dq);
                dk = fmaf(yv, wkp[lane + 64*j], dk);
            }
            #pragma unroll
            for (int off = 32; off; off >>= 1) {
                dq += __shfl_down(dq, off);
                dk += __shfl_down(dk, off);
            }
            if (lane == 0) {
                const float aq = tanhf(dq) * (PI_F * 0.25f);
                const float ak = tanhf(dk) * (PI_F * 0.25f);
                float sv, cv;
                const long o = (long)h * 8192 + row;
                __sincosf(aq, &sv, &cv); cqA[o] = cv; sqA[o] = sv;
                __sincosf(ak, &sv, &cv); ckA[o] = cv; skA[o] = sv;
            }
        }
    }
}

// ---------------------------------------------------------------------------
// Fused cumsum scan + heads: one block (8 waves) per (b, head).
// ---------------------------------------------------------------------------
__global__ __launch_bounds__(512)
void scan_kernel(const u16* __restrict__ V,
                 const float* __restrict__ cqA, const float* __restrict__ sqA,
                 const float* __restrict__ ckA, const float* __restrict__ skA,
                 u16* __restrict__ H)
{
    __shared__ float totcV[8][64], totsV[8][64];
    __shared__ float totc[8], tots[8];
    const int b = blockIdx.x >> 4;
    const int h = blockIdx.x & 15;
    const int wv = threadIdx.x >> 6;
    const int lane = threadIdx.x & 63;
    const long rowbase = (long)b * 2048;
    const long qbase = (long)h * 8192 + rowbase;
    const int t0 = wv * 256;

    const u16* vp = V + (rowbase + t0) * 1024 + (long)h * 64 + lane;

    float tc = 0.f, ts = 0.f, kc = 0.f, ks = 0.f;
    #pragma unroll 4
    for (int tt = 0; tt < 256; ++tt) {
        const float ck = ckA[qbase + t0 + tt];
        const float sk = skA[qbase + t0 + tt];
        const float vx = bf2f(vp[(long)tt * 1024]);
        tc = fmaf(ck, vx, tc); ts = fmaf(sk, vx, ts);
        kc += ck; ks += sk;
    }
    totcV[wv][lane] = tc; totsV[wv][lane] = ts;
    if (lane == 0) { totc[wv] = kc; tots[wv] = ks; }
    __syncthreads();

    float carC = 0.f, carS = 0.f, carKc = 0.f, carKs = 0.f;
    for (int w2 = 0; w2 < wv; ++w2) {
        carC += totcV[w2][lane]; carS += totsV[w2][lane];
        carKc += totc[w2]; carKs += tots[w2];
    }

    float csum = carC, ssum = carS, kcs = carKc, kss = carKs;
    u16* outp = H + (rowbase + t0) * 1024 + (long)h * 64 + lane;
    #pragma unroll 4
    for (int tt = 0; tt < 256; ++tt) {
        const long qo = qbase + t0 + tt;
        const float ck = ckA[qo], sk = skA[qo];
        const float cq = cqA[qo], sq2 = sqA[qo];
        const float vx = bf2f(vp[(long)tt * 1024]);
        csum = fmaf(ck, vx, csum); ssum = fmaf(sk, vx, ssum);
        kcs += ck; kss += sk;
        const float denom = cq * kcs + sq2 * kss + 1e-6f;
        const float hv = (cq * csum + sq2 * ssum) / denom;
        outp[(long)tt * 1024] = f2bf(hv);
    }
}

// ---------------------------------------------------------------------------
// gemm6: BM=256 x BN, BK=64, 8 waves in 1M x 8N layout (wave w owns all 256
// rows x cols [w*BN/8, (w+1)*BN/8)).  Phase q consumes ONLY A rows
// [q*64,q*64+64) -> A staging segments are phase-aligned; B frags loaded once
// per K-tile and held in registers.  2 LDS buffers.  Counted vmcnt only
// (never 0 in loop):
//  BN=256 (4 phases): p0{readB+Aq0, stage Bs01} p1{Aq1, stage Bs23, vmcnt(4)}
//                     p2{Aq2, stage As01} p3{Aq3, stage As23, vmcnt(2)}
//  BN=128 (2 phases): p0{readB+Ah0, stage Bs+As01, vmcnt(4)}
//                     p1{Ah1, stage As23, vmcnt(2)}
// Chunk-rotation swizzle (verified 0-conflict r2-r5): logical 16B chunk c of
// row r at phys (c + r%8)%8; staged via inverse-rotated global source.
// EPI: 0 bf16 store; 1 f32 +res; 2 bf16 gelu(+bias); 3 f32 +res+bias.
// ---------------------------------------------------------------------------
template<int EPI, int BN>
__global__ __launch_bounds__(512, 1)
void gemm6(const u16* __restrict__ A, const u16* __restrict__ B,
           void* __restrict__ Cout, const float* __restrict__ res,
           const float* __restrict__ bias, int N, int K, int nx)
{
    constexpr int NF = BN / 128;            // n-frags per wave: 2 or 1
    constexpr int WC = BN / 8;              // cols per wave: 32 or 16
    __shared__ u16 As[2 * 256 * 64];        // 64 KB
    __shared__ u16 Bs[2 * BN * 64];         // 64 or 32 KB

    const int tid  = threadIdx.x;
    const int lane = tid & 63;
    const int w    = tid >> 6;
    const int rr   = lane & 15;
    const int kq   = lane >> 4;

    const int L = blockIdx.x;
    const int xcd = L & 7;
    const int qq = L >> 3;
    const int brow = ((qq / nx) * 8 + xcd) * 256;
    const int bcol = (qq % nx) * BN;

    // staging map: v = row-in-seg (0..63), chp = phys chunk, clog = src chunk
    const int v = tid >> 3;
    const int chp = tid & 7;
    const int clog = (chp - (v & 7)) & 7;
    const u16* AgB = A + (long)(brow + v) * K + clog * 8;
    const u16* BgB = B + (long)(bcol + v) * K + clog * 8;

    // fragment read offsets (bytes); read-side rotation matches staging.
    const int ph0 = ((kq + (rr & 7)) & 7) * 16;
    const int ph1 = ((kq + 4 + (rr & 7)) & 7) * 16;
    const int arb = rr * 128;

    f32x4 acc[16][NF];
    #pragma unroll
    for (int i = 0; i < 16; ++i)
        #pragma unroll
        for (int j = 0; j < NF; ++j) acc[i][j] = (f32x4){0.f, 0.f, 0.f, 0.f};

    const int NT = K >> 6;

#define SA(nb, kn, s)  glds16(AgB + (kn) + (long)(s) * 64 * K, &As[(nb) * 16384 + (s) * 4096 + tid * 8])
#define SBG(nb, kn, s) glds16(BgB + (kn) + (long)(s) * 64 * K, &Bs[(nb) * (BN * 64) + (s) * 4096 + tid * 8])
#define BAR   asm volatile("s_barrier" ::: "memory")
#define LGKM0 asm volatile("s_waitcnt lgkmcnt(0)" ::: "memory")
#define VMC4  asm volatile("s_waitcnt vmcnt(4)" ::: "memory")
#define VMC2  asm volatile("s_waitcnt vmcnt(2)" ::: "memory")
#define SBR   __builtin_amdgcn_sched_barrier(0)

    // prologue: stage tile 0 fully into buf 0
    if constexpr (BN == 256) { SBG(0,0,0); SBG(0,0,1); SBG(0,0,2); SBG(0,0,3); }
    else                     { SBG(0,0,0); SBG(0,0,1); }
    SA(0,0,0); SA(0,0,1); SA(0,0,2); SA(0,0,3);
    asm volatile("s_waitcnt vmcnt(0)" ::: "memory");
    BAR;

    for (int t = 0; t < NT; ++t) {
        const int cur = t & 1, nxt = cur ^ 1;
        const long kn = (long)((t + 1 < NT) ? (t + 1) : 0) * 64;
        const char* Ap = (const char*)As + cur * 32768;
        const char* Bp = (const char*)Bs + cur * (BN * 128);

        if constexpr (BN == 256) {
            bfx8 bF[4], aF[8];
            // ---- p0: read B frags (held all tile) + A q0; stage B segs 0,1
            #pragma unroll
            for (int nf = 0; nf < 2; ++nf) {
                bF[nf*2+0] = *(const bfx8*)(Bp + w*4096 + nf*2048 + arb + ph0);
                bF[nf*2+1] = *(const bfx8*)(Bp + w*4096 + nf*2048 + arb + ph1);
            }
            #pragma unroll
            for (int mf = 0; mf < 4; ++mf) {
                aF[mf*2+0] = *(const bfx8*)(Ap + mf*2048 + arb + ph0);
                aF[mf*2+1] = *(const bfx8*)(Ap + mf*2048 + arb + ph1);
            }
            SBG(nxt, kn, 0); SBG(nxt, kn, 1);
            BAR; LGKM0; SBR;
            __builtin_amdgcn_s_setprio(1);
            #pragma unroll
            for (int mf = 0; mf < 4; ++mf)
                #pragma unroll
                for (int nf = 0; nf < 2; ++nf) {
                    acc[mf][nf] = __builtin_amdgcn_mfma_f32_16x16x32_bf16(aF[mf*2+0], bF[nf*2+0], acc[mf][nf], 0, 0, 0);
                    acc[mf][nf] = __builtin_amdgcn_mfma_f32_16x16x32_bf16(aF[mf*2+1], bF[nf*2+1], acc[mf][nf], 0, 0, 0);
                }
            __builtin_amdgcn_s_setprio(0); SBR; BAR;
            // ---- p1: A q1; stage B segs 2,3; vmcnt(4)
            #pragma unroll
            for (int mf = 0; mf < 4; ++mf) {
                aF[mf*2+0] = *(const bfx8*)(Ap + 8192 + mf*2048 + arb + ph0);
                aF[mf*2+1] = *(const bfx8*)(Ap + 8192 + mf*2048 + arb + ph1);
            }
            SBG(nxt, kn, 2); SBG(nxt, kn, 3);
            BAR; LGKM0; SBR;
            __builtin_amdgcn_s_setprio(1);
            #pragma unroll
            for (int mf = 0; mf < 4; ++mf)
                #pragma unroll
                for (int nf = 0; nf < 2; ++nf) {
                    acc[4+mf][nf] = __builtin_amdgcn_mfma_f32_16x16x32_bf16(aF[mf*2+0], bF[nf*2+0], acc[4+mf][nf], 0, 0, 0);
                    acc[4+mf][nf] = __builtin_amdgcn_mfma_f32_16x16x32_bf16(aF[mf*2+1], bF[nf*2+1], acc[4+mf][nf], 0, 0, 0);
                }
            __builtin_amdgcn_s_setprio(0); SBR; VMC4; BAR;
            // ---- p2: A q2; stage A segs 0,1
            #pragma unroll
            for (int mf = 0; mf < 4; ++mf) {
                aF[mf*2+0] = *(const bfx8*)(Ap + 16384 + mf*2048 + arb + ph0);
                aF[mf*2+1] = *(const bfx8*)(Ap + 16384 + mf*2048 + arb + ph1);
            }
            SA(nxt, kn, 0); SA(nxt, kn, 1);
            BAR; LGKM0; SBR;
            __builtin_amdgcn_s_setprio(1);
            #pragma unroll
            for (int mf = 0; mf < 4; ++mf)
                #pragma unroll
                for (int nf = 0; nf < 2; ++nf) {
                    acc[8+mf][nf] = __builtin_amdgcn_mfma_f32_16x16x32_bf16(aF[mf*2+0], bF[nf*2+0], acc[8+mf][nf], 0, 0, 0);
                    acc[8+mf][nf] = __builtin_amdgcn_mfma_f32_16x16x32_bf16(aF[mf*2+1], bF[nf*2+1], acc[8+mf][nf], 0, 0, 0);
                }
            __builtin_amdgcn_s_setprio(0); SBR; BAR;
            // ---- p3: A q3; stage A segs 2,3; vmcnt(2)
            #pragma unroll
            for (int mf = 0; mf < 4; ++mf) {
                aF[mf*2+0] = *(const bfx8*)(Ap + 24576 + mf*2048 + arb + ph0);
                aF[mf*2+1] = *(const bfx8*)(Ap + 24576 + mf*2048 + arb + ph1);
            }
            SA(nxt, kn, 2); SA(nxt, kn, 3);
            BAR; LGKM0; SBR;
            __builtin_amdgcn_s_setprio(1);
            #pragma unroll
            for (int mf = 0; mf < 4; ++mf)
                #pragma unroll
                for (int nf = 0; nf < 2; ++nf) {
                    acc[12+mf][nf] = __builtin_amdgcn_mfma_f32_16x16x32_bf16(aF[mf*2+0], bF[nf*2+0], acc[12+mf][nf], 0, 0, 0);
                    acc[12+mf][nf] = __builtin_amdgcn_mfma_f32_16x16x32_bf16(aF[mf*2+1], bF[nf*2+1], acc[12+mf][nf], 0, 0, 0);
                }
            __builtin_amdgcn_s_setprio(0); SBR; VMC2; BAR;
        } else {
            bfx8 bF[2], aF[16];
            // ---- p0: read B frags + A rows 0-127; stage B(2) + A segs 0,1
            bF[0] = *(const bfx8*)(Bp + w*2048 + arb + ph0);
            bF[1] = *(const bfx8*)(Bp + w*2048 + arb + ph1);
            #pragma unroll
            for (int mf = 0; mf < 8; ++mf) {
                aF[mf*2+0] = *(const bfx8*)(Ap + mf*2048 + arb + ph0);
                aF[mf*2+1] = *(const bfx8*)(Ap + mf*2048 + arb + ph1);
            }
            SBG(nxt, kn, 0); SBG(nxt, kn, 1); SA(nxt, kn, 0); SA(nxt, kn, 1);
            BAR; LGKM0; SBR;
            __builtin_amdgcn_s_setprio(1);
            #pragma unroll
            for (int mf = 0; mf < 8; ++mf) {
                acc[mf][0] = __builtin_amdgcn_mfma_f32_16x16x32_bf16(aF[mf*2+0], bF[0], acc[mf][0], 0, 0, 0);
                acc[mf][0] = __builtin_amdgcn_mfma_f32_16x16x32_bf16(aF[mf*2+1], bF[1], acc[mf][0], 0, 0, 0);
            }
            __builtin_amdgcn_s_setprio(0); SBR; VMC4; BAR;
            // ---- p1: A rows 128-255; stage A segs 2,3; vmcnt(2)
            #pragma unroll
            for (int mf = 0; mf < 8; ++mf) {
                aF[mf*2+0] = *(const bfx8*)(Ap + 16384 + mf*2048 + arb + ph0);
                aF[mf*2+1] = *(const bfx8*)(Ap + 16384 + mf*2048 + arb + ph1);
            }
            SA(nxt, kn, 2); SA(nxt, kn, 3);
            BAR; LGKM0; SBR;
            __builtin_amdgcn_s_setprio(1);
            #pragma unroll
            for (int mf = 0; mf < 8; ++mf) {
                acc[8+mf][0] = __builtin_amdgcn_mfma_f32_16x16x32_bf16(aF[mf*2+0], bF[0], acc[8+mf][0], 0, 0, 0);
                acc[8+mf][0] = __builtin_amdgcn_mfma_f32_16x16x32_bf16(aF[mf*2+1], bF[1], acc[8+mf][0], 0, 0, 0);
            }
            __builtin_amdgcn_s_setprio(0); SBR; VMC2; BAR;
        }
    }
    asm volatile("s_waitcnt vmcnt(0)" ::: "memory");

#undef SA
#undef SBG
#undef BAR
#undef LGKM0
#undef VMC4
#undef VMC2
#undef SBR

    // epilogue: row = brow + ai*16 + kq*4 + r; col = bcol + w*WC + nf*16 + rr
    #pragma unroll
    for (int ai = 0; ai < 16; ++ai) {
        #pragma unroll
        for (int nf = 0; nf < NF; ++nf) {
            const int col = bcol + w * WC + nf * 16 + rr;
            #pragma unroll
            for (int r = 0; r < 4; ++r) {
                const int row = brow + ai * 16 + kq * 4 + r;
                const long idx = (long)row * N + col;
                const float vv = acc[ai][nf][r];
                if (EPI == 0) {
                    ((u16*)Cout)[idx] = f2bf(vv);
                } else if (EPI == 1) {
                    ((float*)Cout)[idx] = vv + res[idx];
                } else if (EPI == 2) {
                    const float hh = vv + bias[col];
                    const float z = 0.7978845608028654f * (hh + 0.044715f * hh * hh * hh);
                    const float e = __expf(2.f * z);
                    const float th = 1.f - 2.f / (e + 1.f);
                    ((u16*)Cout)[idx] = f2bf(0.5f * hh * (1.f + th));
                } else {
                    ((float*)Cout)[idx] = vv + res[idx] + bias[col];
                }
            }
        }
    }
}

// ---------------------------------------------------------------------------
extern "C" void kernel_launch(void* const* d_in, const int* in_sizes, int n_in,
                              void* d_out, int out_size, void* d_ws, size_t ws_size,
                              hipStream_t stream)
{
    (void)in_sizes; (void)n_in; (void)out_size; (void)ws_size;
    const float* x    = (const float*)d_in[0];
    const float* WQ   = (const float*)d_in[1];
    const float* WK   = (const float*)d_in[2];
    const float* WV   = (const float*)d_in[3];
    const float* WO   = (const float*)d_in[4];
    const float* ln1w = (const float*)d_in[5];
    const float* ln1b = (const float*)d_in[6];
    const float* ln2w = (const float*)d_in[7];
    const float* ln2b = (const float*)d_in[8];
    const float* W1   = (const float*)d_in[9];
    const float* b1   = (const float*)d_in[10];
    const float* W2   = (const float*)d_in[11];
    const float* b2   = (const float*)d_in[12];
    float* out = (float*)d_out;

    char* ws = (char*)d_ws;
    u16*   Ybf  = (u16*)(ws + 0);                    // 16 MB (reused as y2)
    u16*   Vbf  = (u16*)(ws + 16777216);             // 16 MB
    u16*   Hbf  = (u16*)(ws + 33554432);             // 16 MB
    float* X2   = (float*)(ws + 50331648);           // 32 MB
    u16*   H1   = (u16*)(ws + 83886080);             // 64 MB
    u16*   WVT  = (u16*)(ws + 150994944);            //  2 MB
    u16*   WOT  = (u16*)(ws + 153092096);            //  2 MB
    u16*   W1T  = (u16*)(ws + 155189248);            //  8 MB
    u16*   W2T  = (u16*)(ws + 163577856);            //  8 MB
    float* CQ   = (float*)(ws + 171966464);
    float* SQ   = (float*)(ws + 172490752);
    float* CK   = (float*)(ws + 173015040);
    float* SK   = (float*)(ws + 173539328);

    // weight transposes/converts to Bt[n][k] bf16
    tconv_kernel<<<dim3(1, 16, 16), 256, 0, stream>>>(WV, WVT, 1024, 64, 1024L*64, 64L*1024);
    tconv_kernel<<<dim3(1, 1, 1024), 256, 0, stream>>>(WO, WOT, 64, 16, 1024L, 1024L);
    tconv_kernel<<<dim3(64, 16, 1), 256, 0, stream>>>(W1, W1T, 1024, 4096, 0L, 0L);
    tconv_kernel<<<dim3(16, 64, 1), 256, 0, stream>>>(W2, W2T, 4096, 1024, 0L, 0L);

    // LN1 + q/k rank-1 projections + tanh/cos/sin
    ln_kernel<true><<<8192, 256, 0, stream>>>(x, ln1w, ln1b, Ybf, WQ, WK, CQ, SQ, CK, SK);

    // V = y @ Wv   (8192x1024x1024)
    gemm6<0, 128><<<256, 512, 0, stream>>>(Ybf, WVT, Vbf, nullptr, nullptr, 1024, 1024, 8);

    // cumsum scan + heads
    scan_kernel<<<64, 512, 0, stream>>>(Vbf, CQ, SQ, CK, SK, Hbf);

    // x2 = x + heads @ Wo   (8192x1024x1024)
    gemm6<1, 128><<<256, 512, 0, stream>>>(Hbf, WOT, X2, x, nullptr, 1024, 1024, 8);

    // LN2 (y2 reuses Ybf)
    ln_kernel<false><<<8192, 256, 0, stream>>>(X2, ln2w, ln2b, Ybf,
                                               nullptr, nullptr, nullptr, nullptr, nullptr, nullptr);

    // h1 = gelu(y2 @ W1 + b1)  (8192x4096x1024)
    gemm6<2, 256><<<512, 512, 0, stream>>>(Ybf, W1T, H1, nullptr, b1, 4096, 1024, 16);

    // out = x2 + h1 @ W2 + b2  (8192x1024x4096)
    gemm6<3, 128><<<256, 512, 0, stream>>>(H1, W2T, out, X2, b2, 1024, 4096, 8);
}

// Round 7
// 509.768 us; speedup vs baseline: 1.0023x; 1.0023x over previous
//
#include <hip/hip_runtime.h>
#include <hip/hip_bf16.h>
#include <stdint.h>

typedef unsigned short u16;
typedef __attribute__((ext_vector_type(4))) unsigned int u32x4;
typedef __attribute__((ext_vector_type(8))) __bf16 bfx8;
typedef __attribute__((ext_vector_type(4))) float f32x4;

#define PI_F 3.14159265358979323846f

__device__ __forceinline__ float bf2f(u16 u) {
    unsigned v = ((unsigned)u) << 16; float f; __builtin_memcpy(&f, &v, 4); return f;
}
__device__ __forceinline__ u16 f2bf(float f) {
    unsigned u; __builtin_memcpy(&u, &f, 4);
    unsigned r = (u + 0x7fffu + ((u >> 16) & 1u)) >> 16; return (u16)r;
}

// global -> LDS direct DMA, 16B per lane. LDS dest must be lane-linear.
__device__ __forceinline__ void glds16(const u16* g, const u16* l) {
    __builtin_amdgcn_global_load_lds(
        (const __attribute__((address_space(1))) unsigned int*)(unsigned long long)g,
        (__attribute__((address_space(3))) unsigned int*)(unsigned int)(unsigned long long)l,
        16, 0, 0);
}

// ---------------------------------------------------------------------------
// Generic tiled transpose + f32->bf16 convert:  out[c][r] = in[r][c], batched.
// ---------------------------------------------------------------------------
__global__ __launch_bounds__(256)
void tconv_kernel(const float* __restrict__ in, u16* __restrict__ out,
                  int R, int C, long inBatch, long outBatch)
{
    __shared__ float tile[64][65];
    const int tx = threadIdx.x & 63;
    const int ty = threadIdx.x >> 6;
    const int bc = blockIdx.x * 64;
    const int br = blockIdx.y * 64;
    const float* ip = in + (long)blockIdx.z * inBatch;
    u16* op = out + (long)blockIdx.z * outBatch;

    #pragma unroll
    for (int rr = ty; rr < 64; rr += 4) {
        int r = br + rr, c = bc + tx;
        tile[rr][tx] = (r < R && c < C) ? ip[(long)r * C + c] : 0.f;
    }
    __syncthreads();
    #pragma unroll
    for (int rr = ty; rr < 64; rr += 4) {
        int oc = bc + rr;
        int orr = br + tx;
        if (oc < C && orr < R)
            op[(long)oc * R + orr] = f2bf(tile[tx][rr]);
    }
}

// ---------------------------------------------------------------------------
// LayerNorm (+ optional rank-1 q/k projections via coalesced float4 dots).
// ---------------------------------------------------------------------------
template<bool DO_QK>
__global__ __launch_bounds__(256)
void ln_kernel(const float* __restrict__ X, const float* __restrict__ w,
               const float* __restrict__ b, u16* __restrict__ Ybf,
               const float* __restrict__ WQ, const float* __restrict__ WK,
               float* __restrict__ cqA, float* __restrict__ sqA,
               float* __restrict__ ckA, float* __restrict__ skA)
{
    __shared__ float wsum[4], wsq[4];
    const int row = blockIdx.x;
    const int tid = threadIdx.x;
    const int lane = tid & 63;
    const int wv = tid >> 6;

    const float4 xv = ((const float4*)(X + (long)row * 1024))[tid];
    float s  = xv.x + xv.y + xv.z + xv.w;
    float sq = xv.x*xv.x + xv.y*xv.y + xv.z*xv.z + xv.w*xv.w;
    #pragma unroll
    for (int off = 32; off; off >>= 1) {
        s  += __shfl_down(s, off);
        sq += __shfl_down(sq, off);
    }
    if (lane == 0) { wsum[wv] = s; wsq[wv] = sq; }
    __syncthreads();
    const float ts = wsum[0] + wsum[1] + wsum[2] + wsum[3];
    const float tq = wsq[0] + wsq[1] + wsq[2] + wsq[3];
    const float mean = ts * (1.f / 1024.f);
    const float var  = tq * (1.f / 1024.f) - mean * mean;
    const float rstd = rsqrtf(var + 1e-5f);

    const float4 wv4 = ((const float4*)w)[tid];
    const float4 bv4 = ((const float4*)b)[tid];
    const float y0 = (xv.x - mean) * rstd * wv4.x + bv4.x;
    const float y1 = (xv.y - mean) * rstd * wv4.y + bv4.y;
    const float y2 = (xv.z - mean) * rstd * wv4.z + bv4.z;
    const float y3 = (xv.w - mean) * rstd * wv4.w + bv4.w;

    uint2 p;
    p.x = (unsigned)f2bf(y0) | ((unsigned)f2bf(y1) << 16);
    p.y = (unsigned)f2bf(y2) | ((unsigned)f2bf(y3) << 16);
    ((uint2*)(Ybf + (long)row * 1024))[tid] = p;

    if constexpr (DO_QK) {
        __shared__ float redq[16][4], redk[16][4];
        #pragma unroll
        for (int h = 0; h < 16; ++h) {
            const float4 q4 = ((const float4*)WQ)[h * 256 + tid];
            const float4 k4 = ((const float4*)WK)[h * 256 + tid];
            float dq = y0*q4.x + y1*q4.y + y2*q4.z + y3*q4.w;
            float dk = y0*k4.x + y1*k4.y + y2*k4.z + y3*k4.w;
            #pragma unroll
            for (int off = 32; off; off >>= 1) {
                dq += __shfl_down(dq, off);
                dk += __shfl_down(dk, off);
            }
            if (lane == 0) { redq[h][wv] = dq; redk[h][wv] = dk; }
        }
        __syncthreads();
        if (tid < 32) {
            const int h = tid >> 1;
            const bool isk = tid & 1;
            const float* rp = isk ? &redk[h][0] : &redq[h][0];
            const float d = rp[0] + rp[1] + rp[2] + rp[3];
            const float a = tanhf(d) * (PI_F * 0.25f);
            float sv, cv; __sincosf(a, &sv, &cv);
            const long o = (long)h * 8192 + row;
            if (isk) { ckA[o] = cv; skA[o] = sv; }
            else     { cqA[o] = cv; sqA[o] = sv; }
        }
    }
}

// ---------------------------------------------------------------------------
// Hierarchical cumsum scan, 3 kernels.
// Groups of 32 rows; 64 groups per (b,h); 64 (b,h) pairs.
// PT layout: [bh*64+g][128] floats (tc[64], ts[64]); PS: [bh*64+g][2].
// ---------------------------------------------------------------------------
__global__ __launch_bounds__(256)
void scanP(const u16* __restrict__ V, const float* __restrict__ ckA,
           const float* __restrict__ skA,
           float* __restrict__ PT, float* __restrict__ PS)
{
    const int bh = blockIdx.x >> 4;
    const int macro = blockIdx.x & 15;
    const int b = bh >> 4, h = bh & 15;
    const int sub = threadIdx.x >> 6, c = threadIdx.x & 63;
    const int g = macro * 4 + sub;
    const int r0 = macro * 128 + sub * 32;
    const long vbase = ((long)b * 2048 + r0) * 1024 + h * 64 + c;
    const long qb = (long)h * 8192 + b * 2048 + r0;

    float tc = 0.f, ts = 0.f, kc = 0.f, ks = 0.f;
    #pragma unroll 8
    for (int i = 0; i < 32; ++i) {
        const float ck = ckA[qb + i], sk = skA[qb + i];
        const float v = bf2f(V[vbase + (long)i * 1024]);
        tc = fmaf(ck, v, tc); ts = fmaf(sk, v, ts);
        kc += ck; ks += sk;
    }
    float* pt = PT + (long)(bh * 64 + g) * 128;
    pt[c] = tc; pt[64 + c] = ts;
    if (c == 0) {
        PS[(bh * 64 + g) * 2 + 0] = kc;
        PS[(bh * 64 + g) * 2 + 1] = ks;
    }
}

// in-place exclusive prefix over the 64 groups of each (b,h)
__global__ __launch_bounds__(64)
void scanS(float* __restrict__ PT, float* __restrict__ PS)
{
    const int bh = blockIdx.x;
    const int c = threadIdx.x;
    float ac = 0.f, as = 0.f, akc = 0.f, aks = 0.f;
    for (int g = 0; g < 64; ++g) {
        float* pt = PT + (long)(bh * 64 + g) * 128;
        const float pc = pt[c], ps = pt[64 + c];
        pt[c] = ac; pt[64 + c] = as;
        ac += pc; as += ps;
        if (c == 0) {
            float* pss = PS + (bh * 64 + g) * 2;
            const float k0 = pss[0], k1 = pss[1];
            pss[0] = akc; pss[1] = aks;
            akc += k0; aks += k1;
        }
    }
}

__global__ __launch_bounds__(256)
void scanE(const u16* __restrict__ V,
           const float* __restrict__ cqA, const float* __restrict__ sqA,
           const float* __restrict__ ckA, const float* __restrict__ skA,
           const float* __restrict__ PT, const float* __restrict__ PS,
           u16* __restrict__ H)
{
    const int bh = blockIdx.x >> 4;
    const int macro = blockIdx.x & 15;
    const int b = bh >> 4, h = bh & 15;
    const int sub = threadIdx.x >> 6, c = threadIdx.x & 63;
    const int g = macro * 4 + sub;
    const int r0 = macro * 128 + sub * 32;
    const long vbase = ((long)b * 2048 + r0) * 1024 + h * 64 + c;
    const long qb = (long)h * 8192 + b * 2048 + r0;

    const float* pt = PT + (long)(bh * 64 + g) * 128;
    float csum = pt[c], ssum = pt[64 + c];
    float kcs = PS[(bh * 64 + g) * 2 + 0];
    float kss = PS[(bh * 64 + g) * 2 + 1];
    u16* hp = H + vbase;
    #pragma unroll 4
    for (int i = 0; i < 32; ++i) {
        const float ck = ckA[qb + i], sk = skA[qb + i];
        const float cq = cqA[qb + i], sq2 = sqA[qb + i];
        const float v = bf2f(V[vbase + (long)i * 1024]);
        csum = fmaf(ck, v, csum); ssum = fmaf(sk, v, ssum);
        kcs += ck; kss += sk;
        const float denom = cq * kcs + sq2 * kss + 1e-6f;
        hp[(long)i * 1024] = f2bf((cq * csum + sq2 * ssum) / denom);
    }
}

// ---------------------------------------------------------------------------
// gemm6: BM=256 x BN, BK=64, 8 waves in 1M x 8N layout. (unchanged from r6)
// ---------------------------------------------------------------------------
template<int EPI, int BN>
__global__ __launch_bounds__(512, 1)
void gemm6(const u16* __restrict__ A, const u16* __restrict__ B,
           void* __restrict__ Cout, const float* __restrict__ res,
           const float* __restrict__ bias, int N, int K, int nx)
{
    constexpr int NF = BN / 128;
    constexpr int WC = BN / 8;
    __shared__ u16 As[2 * 256 * 64];
    __shared__ u16 Bs[2 * BN * 64];

    const int tid  = threadIdx.x;
    const int lane = tid & 63;
    const int w    = tid >> 6;
    const int rr   = lane & 15;
    const int kq   = lane >> 4;

    const int L = blockIdx.x;
    const int xcd = L & 7;
    const int qq = L >> 3;
    const int brow = ((qq / nx) * 8 + xcd) * 256;
    const int bcol = (qq % nx) * BN;

    const int v = tid >> 3;
    const int chp = tid & 7;
    const int clog = (chp - (v & 7)) & 7;
    const u16* AgB = A + (long)(brow + v) * K + clog * 8;
    const u16* BgB = B + (long)(bcol + v) * K + clog * 8;

    const int ph0 = ((kq + (rr & 7)) & 7) * 16;
    const int ph1 = ((kq + 4 + (rr & 7)) & 7) * 16;
    const int arb = rr * 128;

    f32x4 acc[16][NF];
    #pragma unroll
    for (int i = 0; i < 16; ++i)
        #pragma unroll
        for (int j = 0; j < NF; ++j) acc[i][j] = (f32x4){0.f, 0.f, 0.f, 0.f};

    const int NT = K >> 6;

#define SA(nb, kn, s)  glds16(AgB + (kn) + (long)(s) * 64 * K, &As[(nb) * 16384 + (s) * 4096 + tid * 8])
#define SBG(nb, kn, s) glds16(BgB + (kn) + (long)(s) * 64 * K, &Bs[(nb) * (BN * 64) + (s) * 4096 + tid * 8])
#define BAR   asm volatile("s_barrier" ::: "memory")
#define LGKM0 asm volatile("s_waitcnt lgkmcnt(0)" ::: "memory")
#define VMC4  asm volatile("s_waitcnt vmcnt(4)" ::: "memory")
#define VMC2  asm volatile("s_waitcnt vmcnt(2)" ::: "memory")
#define SBR   __builtin_amdgcn_sched_barrier(0)

    if constexpr (BN == 256) { SBG(0,0,0); SBG(0,0,1); SBG(0,0,2); SBG(0,0,3); }
    else                     { SBG(0,0,0); SBG(0,0,1); }
    SA(0,0,0); SA(0,0,1); SA(0,0,2); SA(0,0,3);
    asm volatile("s_waitcnt vmcnt(0)" ::: "memory");
    BAR;

    for (int t = 0; t < NT; ++t) {
        const int cur = t & 1, nxt = cur ^ 1;
        const long kn = (long)((t + 1 < NT) ? (t + 1) : 0) * 64;
        const char* Ap = (const char*)As + cur * 32768;
        const char* Bp = (const char*)Bs + cur * (BN * 128);

        if constexpr (BN == 256) {
            bfx8 bF[4], aF[8];
            #pragma unroll
            for (int nf = 0; nf < 2; ++nf) {
                bF[nf*2+0] = *(const bfx8*)(Bp + w*4096 + nf*2048 + arb + ph0);
                bF[nf*2+1] = *(const bfx8*)(Bp + w*4096 + nf*2048 + arb + ph1);
            }
            #pragma unroll
            for (int mf = 0; mf < 4; ++mf) {
                aF[mf*2+0] = *(const bfx8*)(Ap + mf*2048 + arb + ph0);
                aF[mf*2+1] = *(const bfx8*)(Ap + mf*2048 + arb + ph1);
            }
            SBG(nxt, kn, 0); SBG(nxt, kn, 1);
            BAR; LGKM0; SBR;
            __builtin_amdgcn_s_setprio(1);
            #pragma unroll
            for (int mf = 0; mf < 4; ++mf)
                #pragma unroll
                for (int nf = 0; nf < 2; ++nf) {
                    acc[mf][nf] = __builtin_amdgcn_mfma_f32_16x16x32_bf16(aF[mf*2+0], bF[nf*2+0], acc[mf][nf], 0, 0, 0);
                    acc[mf][nf] = __builtin_amdgcn_mfma_f32_16x16x32_bf16(aF[mf*2+1], bF[nf*2+1], acc[mf][nf], 0, 0, 0);
                }
            __builtin_amdgcn_s_setprio(0); SBR; BAR;
            #pragma unroll
            for (int mf = 0; mf < 4; ++mf) {
                aF[mf*2+0] = *(const bfx8*)(Ap + 8192 + mf*2048 + arb + ph0);
                aF[mf*2+1] = *(const bfx8*)(Ap + 8192 + mf*2048 + arb + ph1);
            }
            SBG(nxt, kn, 2); SBG(nxt, kn, 3);
            BAR; LGKM0; SBR;
            __builtin_amdgcn_s_setprio(1);
            #pragma unroll
            for (int mf = 0; mf < 4; ++mf)
                #pragma unroll
                for (int nf = 0; nf < 2; ++nf) {
                    acc[4+mf][nf] = __builtin_amdgcn_mfma_f32_16x16x32_bf16(aF[mf*2+0], bF[nf*2+0], acc[4+mf][nf], 0, 0, 0);
                    acc[4+mf][nf] = __builtin_amdgcn_mfma_f32_16x16x32_bf16(aF[mf*2+1], bF[nf*2+1], acc[4+mf][nf], 0, 0, 0);
                }
            __builtin_amdgcn_s_setprio(0); SBR; VMC4; BAR;
            #pragma unroll
            for (int mf = 0; mf < 4; ++mf) {
                aF[mf*2+0] = *(const bfx8*)(Ap + 16384 + mf*2048 + arb + ph0);
                aF[mf*2+1] = *(const bfx8*)(Ap + 16384 + mf*2048 + arb + ph1);
            }
            SA(nxt, kn, 0); SA(nxt, kn, 1);
            BAR; LGKM0; SBR;
            __builtin_amdgcn_s_setprio(1);
            #pragma unroll
            for (int mf = 0; mf < 4; ++mf)
                #pragma unroll
                for (int nf = 0; nf < 2; ++nf) {
                    acc[8+mf][nf] = __builtin_amdgcn_mfma_f32_16x16x32_bf16(aF[mf*2+0], bF[nf*2+0], acc[8+mf][nf], 0, 0, 0);
                    acc[8+mf][nf] = __builtin_amdgcn_mfma_f32_16x16x32_bf16(aF[mf*2+1], bF[nf*2+1], acc[8+mf][nf], 0, 0, 0);
                }
            __builtin_amdgcn_s_setprio(0); SBR; BAR;
            #pragma unroll
            for (int mf = 0; mf < 4; ++mf) {
                aF[mf*2+0] = *(const bfx8*)(Ap + 24576 + mf*2048 + arb + ph0);
                aF[mf*2+1] = *(const bfx8*)(Ap + 24576 + mf*2048 + arb + ph1);
            }
            SA(nxt, kn, 2); SA(nxt, kn, 3);
            BAR; LGKM0; SBR;
            __builtin_amdgcn_s_setprio(1);
            #pragma unroll
            for (int mf = 0; mf < 4; ++mf)
                #pragma unroll
                for (int nf = 0; nf < 2; ++nf) {
                    acc[12+mf][nf] = __builtin_amdgcn_mfma_f32_16x16x32_bf16(aF[mf*2+0], bF[nf*2+0], acc[12+mf][nf], 0, 0, 0);
                    acc[12+mf][nf] = __builtin_amdgcn_mfma_f32_16x16x32_bf16(aF[mf*2+1], bF[nf*2+1], acc[12+mf][nf], 0, 0, 0);
                }
            __builtin_amdgcn_s_setprio(0); SBR; VMC2; BAR;
        } else {
            bfx8 bF[2], aF[16];
            bF[0] = *(const bfx8*)(Bp + w*2048 + arb + ph0);
            bF[1] = *(const bfx8*)(Bp + w*2048 + arb + ph1);
            #pragma unroll
            for (int mf = 0; mf < 8; ++mf) {
                aF[mf*2+0] = *(const bfx8*)(Ap + mf*2048 + arb + ph0);
                aF[mf*2+1] = *(const bfx8*)(Ap + mf*2048 + arb + ph1);
            }
            SBG(nxt, kn, 0); SBG(nxt, kn, 1); SA(nxt, kn, 0); SA(nxt, kn, 1);
            BAR; LGKM0; SBR;
            __builtin_amdgcn_s_setprio(1);
            #pragma unroll
            for (int mf = 0; mf < 8; ++mf) {
                acc[mf][0] = __builtin_amdgcn_mfma_f32_16x16x32_bf16(aF[mf*2+0], bF[0], acc[mf][0], 0, 0, 0);
                acc[mf][0] = __builtin_amdgcn_mfma_f32_16x16x32_bf16(aF[mf*2+1], bF[1], acc[mf][0], 0, 0, 0);
            }
            __builtin_amdgcn_s_setprio(0); SBR; VMC4; BAR;
            #pragma unroll
            for (int mf = 0; mf < 8; ++mf) {
                aF[mf*2+0] = *(const bfx8*)(Ap + 16384 + mf*2048 + arb + ph0);
                aF[mf*2+1] = *(const bfx8*)(Ap + 16384 + mf*2048 + arb + ph1);
            }
            SA(nxt, kn, 2); SA(nxt, kn, 3);
            BAR; LGKM0; SBR;
            __builtin_amdgcn_s_setprio(1);
            #pragma unroll
            for (int mf = 0; mf < 8; ++mf) {
                acc[8+mf][0] = __builtin_amdgcn_mfma_f32_16x16x32_bf16(aF[mf*2+0], bF[0], acc[8+mf][0], 0, 0, 0);
                acc[8+mf][0] = __builtin_amdgcn_mfma_f32_16x16x32_bf16(aF[mf*2+1], bF[1], acc[8+mf][0], 0, 0, 0);
            }
            __builtin_amdgcn_s_setprio(0); SBR; VMC2; BAR;
        }
    }
    asm volatile("s_waitcnt vmcnt(0)" ::: "memory");

#undef SA
#undef SBG
#undef BAR
#undef LGKM0
#undef VMC4
#undef VMC2
#undef SBR

    #pragma unroll
    for (int ai = 0; ai < 16; ++ai) {
        #pragma unroll
        for (int nf = 0; nf < NF; ++nf) {
            const int col = bcol + w * WC + nf * 16 + rr;
            #pragma unroll
            for (int r = 0; r < 4; ++r) {
                const int row = brow + ai * 16 + kq * 4 + r;
                const long idx = (long)row * N + col;
                const float vv = acc[ai][nf][r];
                if (EPI == 0) {
                    ((u16*)Cout)[idx] = f2bf(vv);
                } else if (EPI == 1) {
                    ((float*)Cout)[idx] = vv + res[idx];
                } else if (EPI == 2) {
                    const float hh = vv + bias[col];
                    const float z = 0.7978845608028654f * (hh + 0.044715f * hh * hh * hh);
                    const float e = __expf(2.f * z);
                    const float th = 1.f - 2.f / (e + 1.f);
                    ((u16*)Cout)[idx] = f2bf(0.5f * hh * (1.f + th));
                } else {
                    ((float*)Cout)[idx] = vv + res[idx] + bias[col];
                }
            }
        }
    }
}

// ---------------------------------------------------------------------------
extern "C" void kernel_launch(void* const* d_in, const int* in_sizes, int n_in,
                              void* d_out, int out_size, void* d_ws, size_t ws_size,
                              hipStream_t stream)
{
    (void)in_sizes; (void)n_in; (void)out_size; (void)ws_size;
    const float* x    = (const float*)d_in[0];
    const float* WQ   = (const float*)d_in[1];
    const float* WK   = (const float*)d_in[2];
    const float* WV   = (const float*)d_in[3];
    const float* WO   = (const float*)d_in[4];
    const float* ln1w = (const float*)d_in[5];
    const float* ln1b = (const float*)d_in[6];
    const float* ln2w = (const float*)d_in[7];
    const float* ln2b = (const float*)d_in[8];
    const float* W1   = (const float*)d_in[9];
    const float* b1   = (const float*)d_in[10];
    const float* W2   = (const float*)d_in[11];
    const float* b2   = (const float*)d_in[12];
    float* out = (float*)d_out;

    char* ws = (char*)d_ws;
    u16*   Ybf  = (u16*)(ws + 0);                    // 16 MB (reused as y2)
    u16*   Vbf  = (u16*)(ws + 16777216);             // 16 MB
    u16*   Hbf  = (u16*)(ws + 33554432);             // 16 MB
    float* X2   = (float*)(ws + 50331648);           // 32 MB
    u16*   H1   = (u16*)(ws + 83886080);             // 64 MB
    u16*   WVT  = (u16*)(ws + 150994944);            //  2 MB
    u16*   WOT  = (u16*)(ws + 153092096);            //  2 MB
    u16*   W1T  = (u16*)(ws + 155189248);            //  8 MB
    u16*   W2T  = (u16*)(ws + 163577856);            //  8 MB
    float* CQ   = (float*)(ws + 171966464);
    float* SQ   = (float*)(ws + 172490752);
    float* CK   = (float*)(ws + 173015040);
    float* SK   = (float*)(ws + 173539328);
    float* PT   = (float*)(ws + 174063616);          //  2 MB
    float* PS   = (float*)(ws + 176160768);          // 32 KB

    // weight transposes/converts to Bt[n][k] bf16
    tconv_kernel<<<dim3(1, 16, 16), 256, 0, stream>>>(WV, WVT, 1024, 64, 1024L*64, 64L*1024);
    tconv_kernel<<<dim3(1, 1, 1024), 256, 0, stream>>>(WO, WOT, 64, 16, 1024L, 1024L);
    tconv_kernel<<<dim3(64, 16, 1), 256, 0, stream>>>(W1, W1T, 1024, 4096, 0L, 0L);
    tconv_kernel<<<dim3(16, 64, 1), 256, 0, stream>>>(W2, W2T, 4096, 1024, 0L, 0L);

    // LN1 + q/k rank-1 projections + tanh/cos/sin
    ln_kernel<true><<<8192, 256, 0, stream>>>(x, ln1w, ln1b, Ybf, WQ, WK, CQ, SQ, CK, SK);

    // V = y @ Wv   (8192x1024x1024)
    gemm6<0, 128><<<256, 512, 0, stream>>>(Ybf, WVT, Vbf, nullptr, nullptr, 1024, 1024, 8);

    // hierarchical cumsum scan + heads
    scanP<<<1024, 256, 0, stream>>>(Vbf, CK, SK, PT, PS);
    scanS<<<64, 64, 0, stream>>>(PT, PS);
    scanE<<<1024, 256, 0, stream>>>(Vbf, CQ, SQ, CK, SK, PT, PS, Hbf);

    // x2 = x + heads @ Wo   (8192x1024x1024)
    gemm6<1, 128><<<256, 512, 0, stream>>>(Hbf, WOT, X2, x, nullptr, 1024, 1024, 8);

    // LN2 (y2 reuses Ybf)
    ln_kernel<false><<<8192, 256, 0, stream>>>(X2, ln2w, ln2b, Ybf,
                                               nullptr, nullptr, nullptr, nullptr, nullptr, nullptr);

    // h1 = gelu(y2 @ W1 + b1)  (8192x4096x1024)
    gemm6<2, 256><<<512, 512, 0, stream>>>(Ybf, W1T, H1, nullptr, b1, 4096, 1024, 16);

    // out = x2 + h1 @ W2 + b2  (8192x1024x4096)
    gemm6<3, 128><<<256, 512, 0, stream>>>(H1, W2T, out, X2, b2, 1024, 4096, 8);
}